// Round 1
// baseline (798.686 us; speedup 1.0000x reference)
//
#include <hip/hip_runtime.h>

#define N_NODES   1048576
#define N_GRAPHS  1024
#define F_XDIM    128
#define F_UDIM    128
#define HIDDEN    512
#define F_OUT     128
#define ROWS_PER_BLOCK 256   // nodes per block in segment-sum

// ---------------------------------------------------------------------------
// Kernel 1: per-graph inverse counts via binary search on sorted `batch`.
// counts[g] = lb(g+1) - lb(g); store 1/max(c,1) directly.
// ---------------------------------------------------------------------------
__global__ __launch_bounds__(256) void seg_invcount_kernel(
        const int* __restrict__ batch, float* __restrict__ inv_cnt) {
    int g = blockIdx.x * blockDim.x + threadIdx.x;
    if (g >= N_GRAPHS) return;
    // lower_bound(target)
    auto lb = [&](int target) {
        int lo = 0, hi = N_NODES;
        while (lo < hi) {
            int mid = (lo + hi) >> 1;
            if (batch[mid] < target) lo = mid + 1; else hi = mid;
        }
        return lo;
    };
    int c = lb(g + 1) - lb(g);
    inv_cnt[g] = 1.0f / (float)max(c, 1);
}

// ---------------------------------------------------------------------------
// Kernel 2: segment sum of x over sorted batch.
// Block = 256 threads = 8 groups of 32 lanes. Group handles rows
// row0+g, row0+g+8, ... Each lane owns 4 consecutive feature columns
// (float4). Register accumulator, atomic flush only on segment change.
// ---------------------------------------------------------------------------
__global__ __launch_bounds__(256) void seg_sum_kernel(
        const float* __restrict__ x, const int* __restrict__ batch,
        float* __restrict__ sums) {
    const int grp  = threadIdx.x >> 5;   // 0..7
    const int lane = threadIdx.x & 31;   // 0..31, owns feats [4*lane, 4*lane+4)
    const int row0 = blockIdx.x * ROWS_PER_BLOCK;

    float4 acc = make_float4(0.f, 0.f, 0.f, 0.f);
    int cur = -1;

    for (int r = row0 + grp; r < row0 + ROWS_PER_BLOCK; r += 8) {
        int seg = batch[r];
        float4 v = reinterpret_cast<const float4*>(x + (size_t)r * F_XDIM)[lane];
        if (seg != cur) {
            if (cur >= 0) {
                float* dst = sums + (size_t)cur * F_XDIM + lane * 4;
                atomicAdd(dst + 0, acc.x);
                atomicAdd(dst + 1, acc.y);
                atomicAdd(dst + 2, acc.z);
                atomicAdd(dst + 3, acc.w);
            }
            cur = seg;
            acc = v;
        } else {
            acc.x += v.x; acc.y += v.y; acc.z += v.z; acc.w += v.w;
        }
    }
    if (cur >= 0) {
        float* dst = sums + (size_t)cur * F_XDIM + lane * 4;
        atomicAdd(dst + 0, acc.x);
        atomicAdd(dst + 1, acc.y);
        atomicAdd(dst + 2, acc.z);
        atomicAdd(dst + 3, acc.w);
    }
}

// ---------------------------------------------------------------------------
// Kernel 3: fused MLP. 4 graphs per block, 256 threads.
//   in  = [x_agg | u]            (4 x 256, LDS)
//   h   = relu(in @ W1 + b1)     (4 x 512, LDS)
//   y   = h @ W2 + b2            (4 x 128 -> global)
// Thread t computes hidden cols t and t+256 (phase 1), then output col
// t&127 for a pair of graphs (phase 2). W loads are coalesced; LDS reads
// are same-address broadcasts (conflict-free).
// ---------------------------------------------------------------------------
#define GT 4  // graphs per block
__global__ __launch_bounds__(256) void mlp_kernel(
        const float* __restrict__ sums, const float* __restrict__ inv_cnt,
        const float* __restrict__ u,
        const float* __restrict__ W1, const float* __restrict__ b1,
        const float* __restrict__ W2, const float* __restrict__ b2,
        float* __restrict__ out) {
    __shared__ float in_s[GT][F_XDIM + F_UDIM];  // 4 x 256
    __shared__ float h_s[GT][HIDDEN];            // 4 x 512

    const int t  = threadIdx.x;        // 0..255
    const int g0 = blockIdx.x * GT;

    // stage concat([x_agg, u]) rows
    for (int g = 0; g < GT; ++g) {
        float v;
        if (t < F_XDIM) v = sums[(size_t)(g0 + g) * F_XDIM + t] * inv_cnt[g0 + g];
        else            v = u[(size_t)(g0 + g) * F_UDIM + (t - F_XDIM)];
        in_s[g][t] = v;
    }
    __syncthreads();

    // h = relu(in @ W1 + b1): thread t -> hidden cols t, t+256
    float acc0[GT], acc1[GT];
    {
        float bb0 = b1[t], bb1 = b1[t + 256];
        #pragma unroll
        for (int g = 0; g < GT; ++g) { acc0[g] = bb0; acc1[g] = bb1; }
    }
    for (int k = 0; k < F_XDIM + F_UDIM; ++k) {
        float w0 = W1[(size_t)k * HIDDEN + t];
        float w1 = W1[(size_t)k * HIDDEN + t + 256];
        #pragma unroll
        for (int g = 0; g < GT; ++g) {
            float iv = in_s[g][k];
            acc0[g] = fmaf(iv, w0, acc0[g]);
            acc1[g] = fmaf(iv, w1, acc1[g]);
        }
    }
    #pragma unroll
    for (int g = 0; g < GT; ++g) {
        h_s[g][t]       = fmaxf(acc0[g], 0.f);
        h_s[g][t + 256] = fmaxf(acc1[g], 0.f);
    }
    __syncthreads();

    // y = h @ W2 + b2: thread t -> out col (t&127) for graphs {2*(t>>7), +1}
    const int c  = t & 127;
    const int gp = (t >> 7) * 2;
    float y0 = b2[c], y1 = b2[c];
    for (int k = 0; k < HIDDEN; ++k) {
        float w = W2[(size_t)k * F_OUT + c];
        y0 = fmaf(h_s[gp][k],     w, y0);
        y1 = fmaf(h_s[gp + 1][k], w, y1);
    }
    out[(size_t)(g0 + gp)     * F_OUT + c] = y0;
    out[(size_t)(g0 + gp + 1) * F_OUT + c] = y1;
}

// ---------------------------------------------------------------------------
extern "C" void kernel_launch(void* const* d_in, const int* in_sizes, int n_in,
                              void* d_out, int out_size, void* d_ws, size_t ws_size,
                              hipStream_t stream) {
    const float* x     = (const float*)d_in[0];
    // d_in[1] edge_index, d_in[2] edge_attr: unused by reference
    const float* u     = (const float*)d_in[3];
    const int*   batch = (const int*)  d_in[4];
    const float* W1    = (const float*)d_in[5];
    const float* b1    = (const float*)d_in[6];
    const float* W2    = (const float*)d_in[7];
    const float* b2    = (const float*)d_in[8];
    float* out = (float*)d_out;

    // workspace layout
    float* sums    = (float*)d_ws;                  // [N_GRAPHS * F_XDIM]
    float* inv_cnt = sums + N_GRAPHS * F_XDIM;      // [N_GRAPHS]

    // sums must start at zero (ws is poisoned 0xAA before every launch)
    hipMemsetAsync(sums, 0, N_GRAPHS * F_XDIM * sizeof(float), stream);

    seg_invcount_kernel<<<(N_GRAPHS + 255) / 256, 256, 0, stream>>>(batch, inv_cnt);
    seg_sum_kernel<<<N_NODES / ROWS_PER_BLOCK, 256, 0, stream>>>(x, batch, sums);
    mlp_kernel<<<N_GRAPHS / GT, 256, 0, stream>>>(sums, inv_cnt, u, W1, b1, W2, b2, out);
}

// Round 2
// 752.268 us; speedup vs baseline: 1.0617x; 1.0617x over previous
//
#include <hip/hip_runtime.h>

#define N_NODES   1048576
#define N_GRAPHS  1024
#define F_XDIM    128
#define F_UDIM    128
#define HIDDEN    512
#define F_OUT     128

// ---------------------------------------------------------------------------
// Kernel 1: per-graph mean of x over sorted `batch`. One block per graph.
// Row range [s,e) found by binary search (redundant in all threads; result
// is uniform so no divergence, no broadcast needed). 16 groups of 32 lanes;
// group j accumulates rows s+j, s+j+16, ...; lane owns 4 feature cols
// (float4). Cross-group reduce via LDS, then write mean directly — no
// atomics, no zero-init of the output.
// ---------------------------------------------------------------------------
__global__ __launch_bounds__(512) void seg_mean_kernel(
        const float* __restrict__ x, const int* __restrict__ batch,
        float* __restrict__ x_agg) {
    const int g    = blockIdx.x;
    const int t    = threadIdx.x;
    const int grp  = t >> 5;    // 0..15
    const int lane = t & 31;    // 0..31, owns feats [4*lane, 4*lane+4)

    // s = lower_bound(g), e = lower_bound(g+1) on sorted batch
    int lo = 0, hi = N_NODES;
    while (lo < hi) {
        int mid = (lo + hi) >> 1;
        if (batch[mid] < g) lo = mid + 1; else hi = mid;
    }
    const int s = lo;
    hi = N_NODES;                    // second search: lb(g+1) >= lb(g)=lo
    while (lo < hi) {
        int mid = (lo + hi) >> 1;
        if (batch[mid] < g + 1) lo = mid + 1; else hi = mid;
    }
    const int e = lo;

    float4 acc = make_float4(0.f, 0.f, 0.f, 0.f);
    for (int r = s + grp; r < e; r += 16) {
        float4 v = reinterpret_cast<const float4*>(x + (size_t)r * F_XDIM)[lane];
        acc.x += v.x; acc.y += v.y; acc.z += v.z; acc.w += v.w;
    }

    __shared__ float partial[16][F_XDIM];   // 8 KB
    reinterpret_cast<float4*>(&partial[grp][lane * 4])[0] = acc;
    __syncthreads();

    if (t < F_XDIM) {
        float m = 0.f;
        #pragma unroll
        for (int j = 0; j < 16; ++j) m += partial[j][t];
        const float inv = 1.0f / (float)max(e - s, 1);   // empty graph -> 0
        x_agg[(size_t)g * F_XDIM + t] = m * inv;
    }
}

// ---------------------------------------------------------------------------
// Kernel 2: fused MLP. 4 graphs per block, 256 threads.
//   in  = [x_agg | u]            (4 x 256, LDS)
//   h   = relu(in @ W1 + b1)     (4 x 512, LDS)
//   y   = h @ W2 + b2            (4 x 128 -> global)
// W loads coalesced; LDS reads are same-address broadcasts (conflict-free).
// ---------------------------------------------------------------------------
#define GT 4  // graphs per block
__global__ __launch_bounds__(256) void mlp_kernel(
        const float* __restrict__ x_agg, const float* __restrict__ u,
        const float* __restrict__ W1, const float* __restrict__ b1,
        const float* __restrict__ W2, const float* __restrict__ b2,
        float* __restrict__ out) {
    __shared__ float in_s[GT][F_XDIM + F_UDIM];  // 4 x 256
    __shared__ float h_s[GT][HIDDEN];            // 4 x 512

    const int t  = threadIdx.x;        // 0..255
    const int g0 = blockIdx.x * GT;

    // stage concat([x_agg, u]) rows (x_agg is already mean-scaled)
    for (int g = 0; g < GT; ++g) {
        float v;
        if (t < F_XDIM) v = x_agg[(size_t)(g0 + g) * F_XDIM + t];
        else            v = u[(size_t)(g0 + g) * F_UDIM + (t - F_XDIM)];
        in_s[g][t] = v;
    }
    __syncthreads();

    // h = relu(in @ W1 + b1): thread t -> hidden cols t, t+256
    float acc0[GT], acc1[GT];
    {
        float bb0 = b1[t], bb1 = b1[t + 256];
        #pragma unroll
        for (int g = 0; g < GT; ++g) { acc0[g] = bb0; acc1[g] = bb1; }
    }
    for (int k = 0; k < F_XDIM + F_UDIM; ++k) {
        float w0 = W1[(size_t)k * HIDDEN + t];
        float w1 = W1[(size_t)k * HIDDEN + t + 256];
        #pragma unroll
        for (int g = 0; g < GT; ++g) {
            float iv = in_s[g][k];
            acc0[g] = fmaf(iv, w0, acc0[g]);
            acc1[g] = fmaf(iv, w1, acc1[g]);
        }
    }
    #pragma unroll
    for (int g = 0; g < GT; ++g) {
        h_s[g][t]       = fmaxf(acc0[g], 0.f);
        h_s[g][t + 256] = fmaxf(acc1[g], 0.f);
    }
    __syncthreads();

    // y = h @ W2 + b2: thread t -> out col (t&127) for graphs {2*(t>>7), +1}
    const int c  = t & 127;
    const int gp = (t >> 7) * 2;
    float y0 = b2[c], y1 = b2[c];
    for (int k = 0; k < HIDDEN; ++k) {
        float w = W2[(size_t)k * F_OUT + c];
        y0 = fmaf(h_s[gp][k],     w, y0);
        y1 = fmaf(h_s[gp + 1][k], w, y1);
    }
    out[(size_t)(g0 + gp)     * F_OUT + c] = y0;
    out[(size_t)(g0 + gp + 1) * F_OUT + c] = y1;
}

// ---------------------------------------------------------------------------
extern "C" void kernel_launch(void* const* d_in, const int* in_sizes, int n_in,
                              void* d_out, int out_size, void* d_ws, size_t ws_size,
                              hipStream_t stream) {
    const float* x     = (const float*)d_in[0];
    // d_in[1] edge_index, d_in[2] edge_attr: unused by reference
    const float* u     = (const float*)d_in[3];
    const int*   batch = (const int*)  d_in[4];
    const float* W1    = (const float*)d_in[5];
    const float* b1    = (const float*)d_in[6];
    const float* W2    = (const float*)d_in[7];
    const float* b2    = (const float*)d_in[8];
    float* out = (float*)d_out;

    // workspace: x_agg [N_GRAPHS * F_XDIM] — fully written by K1, no init
    float* x_agg = (float*)d_ws;

    seg_mean_kernel<<<N_GRAPHS, 512, 0, stream>>>(x, batch, x_agg);
    mlp_kernel<<<N_GRAPHS / GT, 256, 0, stream>>>(x_agg, u, W1, b1, W2, b2, out);
}